// Round 7
// baseline (91.134 us; speedup 1.0000x reference)
//
#include <hip/hip_runtime.h>
#include <hip/hip_fp16.h>

#define KFEAT 32
#define NB 8            // batch elements per block
#define XPITCH 544      // floats per element row in xs (8 chunks * 68)
#define APITCH 272      // floats per bag row in accs overlay (= XPITCH/2)

__device__ __forceinline__ float clip01(float v) {
    return fminf(fmaxf(v, 0.0f), 1.0f);
}

// ---------------- fp32 table -> fp16 (RTE) conversion, runs every launch ----------------
__global__ __launch_bounds__(256) void convert_table_f16(
    const float* __restrict__ src, ushort* __restrict__ dst, int n4)
{
    int i = blockIdx.x * blockDim.x + threadIdx.x;
    const int stride = gridDim.x * blockDim.x;
    for (; i < n4; i += stride) {
        const float4 f = reinterpret_cast<const float4*>(src)[i];
        const __half2 h01 = __float22half2_rn(make_float2(f.x, f.y));
        const __half2 h23 = __float22half2_rn(make_float2(f.z, f.w));
        uint2 o;
        o.x = __builtin_bit_cast(uint, h01);
        o.y = __builtin_bit_cast(uint, h23);
        reinterpret_cast<uint2*>(dst)[i] = o;
    }
}

// ---- explicit-pipeline gather primitives (asm loads + counted vmcnt) ----
// One global_load_dwordx2: whole wave reads one 512B fp16 row (SGPR base, voff=l*8).
#define LD(dst, ivr, kk)                                                          \
    {                                                                             \
        const ushort* rp_ = tb + (size_t)__builtin_amdgcn_readlane((ivr), (kk)) * 256; \
        asm volatile("global_load_dwordx2 %0, %1, %2"                             \
                     : "=v"(dst) : "v"(voff), "s"(rp_));                          \
    }
#define LOAD8(ARR, ivr, base)                                                     \
    LD(ARR[0], ivr, (base) + 0) LD(ARR[1], ivr, (base) + 1)                       \
    LD(ARR[2], ivr, (base) + 2) LD(ARR[3], ivr, (base) + 3)                       \
    LD(ARR[4], ivr, (base) + 4) LD(ARR[5], ivr, (base) + 5)                       \
    LD(ARR[6], ivr, (base) + 6) LD(ARR[7], ivr, (base) + 7)

#define ACC1(x)                                                                   \
    {                                                                             \
        const uint lo_ = (uint)(x);                                               \
        const uint hi_ = (uint)((x) >> 32);                                       \
        a01 = __hadd2(a01, __builtin_bit_cast(__half2, lo_));                     \
        a23 = __hadd2(a23, __builtin_bit_cast(__half2, hi_));                     \
    }
#define SUM8(ARR)                                                                 \
    ACC1(ARR[0]) ACC1(ARR[1]) ACC1(ARR[2]) ACC1(ARR[3])                           \
    ACC1(ARR[4]) ACC1(ARR[5]) ACC1(ARR[6]) ACC1(ARR[7])

// Counted wait + full scheduling fence (rule #18: stop VALU hoisting past waitcnt)
#define WAITV(N)                                                                  \
    {                                                                             \
        asm volatile("s_waitcnt vmcnt(" #N ")" ::: "memory");                     \
        __builtin_amdgcn_sched_barrier(0);                                        \
    }

// ---------------- main fused kernel: fp16 table, forced-pipeline gather ----------------
__global__ __launch_bounds__(256, 8) void nnue_f16_kernel(
    const int* __restrict__ wf, const int* __restrict__ bf,
    const float* __restrict__ stm, const ushort* __restrict__ tb,
    const float* __restrict__ ft_bias,
    const float* __restrict__ W1, const float* __restrict__ b1,
    const float* __restrict__ W2, const float* __restrict__ b2,
    const float* __restrict__ Wo, const float* __restrict__ bo,
    float* __restrict__ out)
{
    // Union region: first accs[16][APITCH] (raw bag sums), then xs[8][XPITCH].
    __shared__ float lds[NB * XPITCH];
    __shared__ float y1s[NB][32];

    const int t   = threadIdx.x;
    const int l   = t & 63;
    const int w   = t >> 6;     // wave 0..3
    const int sub = l & 31;
    const int b0  = blockIdx.x * NB;

    // ---- Phase A: gather 16 bags (4 per wave). side is constant per wave. ----
    {
        const int side = w & 1;
        const int eb   = w >> 1;
        const int* fp  = side ? bf : wf;
        const uint voff = (uint)(l * 8);

        int idxv[4];
        #pragma unroll
        for (int g = 0; g < 4; ++g)
            idxv[g] = fp[(size_t)(b0 + 2 * g + eb) * KFEAT + sub];

        #pragma unroll
        for (int g = 0; g < 4; ++g) {
            const int iv  = idxv[g];
            const int bag = g * 4 + w;
            unsigned long long A[8], B[8], C[8], D[8];
            __half2 a01 = __builtin_bit_cast(__half2, 0u);
            __half2 a23 = __builtin_bit_cast(__half2, 0u);

            LOAD8(A, iv, 0)
            LOAD8(B, iv, 8)
            WAITV(8)
            SUM8(A)
            LOAD8(C, iv, 16)
            WAITV(8)
            SUM8(B)
            LOAD8(D, iv, 24)
            WAITV(8)
            SUM8(C)
            WAITV(0)
            SUM8(D)

            const float2 f01 = __half22float2(a01);
            const float2 f23 = __half22float2(a23);
            *reinterpret_cast<float4*>(&lds[bag * APITCH + l * 4]) =
                make_float4(f01.x, f01.y, f23.x, f23.y);
        }
    }
    __syncthreads();

    // ---- Phase B: mix + clip, in-place overlay (read all -> barrier -> write) ----
    {
        const int e = t >> 5, r = t & 31;
        const float s  = stm[b0 + e];
        const float os = 1.0f - s;
        const float4 wa0 = *reinterpret_cast<const float4*>(&lds[(2 * e + 0) * APITCH + 4 * r]);
        const float4 ba0 = *reinterpret_cast<const float4*>(&lds[(2 * e + 1) * APITCH + 4 * r]);
        const float4 wa1 = *reinterpret_cast<const float4*>(&lds[(2 * e + 0) * APITCH + 4 * (r + 32)]);
        const float4 ba1 = *reinterpret_cast<const float4*>(&lds[(2 * e + 1) * APITCH + 4 * (r + 32)]);
        const float4 fb0 = reinterpret_cast<const float4*>(ft_bias)[r];
        const float4 fb1 = reinterpret_cast<const float4*>(ft_bias)[r + 32];
        __syncthreads();

        // d = hf*256 + 4*i  ->  xs addr: e*XPITCH + (d>>6)*68 + (d&63)
        #define MIXW(wa, ba, fb, i, hf)                                              \
        {                                                                            \
            float4 xv;                                                               \
            if (hf == 0) {                                                           \
                xv.x = clip01(fmaf(s, (wa).x, fmaf(os, (ba).x, (fb).x)));            \
                xv.y = clip01(fmaf(s, (wa).y, fmaf(os, (ba).y, (fb).y)));            \
                xv.z = clip01(fmaf(s, (wa).z, fmaf(os, (ba).z, (fb).z)));            \
                xv.w = clip01(fmaf(s, (wa).w, fmaf(os, (ba).w, (fb).w)));            \
            } else {                                                                 \
                xv.x = clip01(fmaf(s, (ba).x, fmaf(os, (wa).x, (fb).x)));            \
                xv.y = clip01(fmaf(s, (ba).y, fmaf(os, (wa).y, (fb).y)));            \
                xv.z = clip01(fmaf(s, (ba).z, fmaf(os, (wa).z, (fb).z)));            \
                xv.w = clip01(fmaf(s, (ba).w, fmaf(os, (wa).w, (fb).w)));            \
            }                                                                        \
            const int d = (hf) * 256 + 4 * (i);                                      \
            *reinterpret_cast<float4*>(&lds[e * XPITCH + (d >> 6) * 68 + (d & 63)]) = xv; \
        }
        MIXW(wa0, ba0, fb0, r,      0)
        MIXW(wa1, ba1, fb1, r + 32, 0)
        MIXW(wa0, ba0, fb0, r,      1)
        MIXW(wa1, ba1, fb1, r + 32, 1)
        #undef MIXW
    }
    __syncthreads();

    // ---- Phase C: layer 1 (512 -> 32) for all 8 elements; W1 read once per block ----
    {
        const int j = t >> 3;   // output neuron 0..31
        const int c = t & 7;    // 64-dim chunk 0..7
        const float* w1p = W1 + j * 512 + c * 64;
        float acc[NB] = {0.f, 0.f, 0.f, 0.f, 0.f, 0.f, 0.f, 0.f};
        #pragma unroll
        for (int blk = 0; blk < 4; ++blk) {
            const float4 wv0 = reinterpret_cast<const float4*>(w1p + blk * 16)[0];
            const float4 wv1 = reinterpret_cast<const float4*>(w1p + blk * 16)[1];
            const float4 wv2 = reinterpret_cast<const float4*>(w1p + blk * 16)[2];
            const float4 wv3 = reinterpret_cast<const float4*>(w1p + blk * 16)[3];
            #pragma unroll
            for (int e = 0; e < NB; ++e) {
                const float* xp = &lds[e * XPITCH + c * 68 + blk * 16];
                const float4 x0 = *reinterpret_cast<const float4*>(xp + 0);
                const float4 x1 = *reinterpret_cast<const float4*>(xp + 4);
                const float4 x2 = *reinterpret_cast<const float4*>(xp + 8);
                const float4 x3 = *reinterpret_cast<const float4*>(xp + 12);
                float a = acc[e];
                a = fmaf(wv0.x, x0.x, a); a = fmaf(wv0.y, x0.y, a);
                a = fmaf(wv0.z, x0.z, a); a = fmaf(wv0.w, x0.w, a);
                a = fmaf(wv1.x, x1.x, a); a = fmaf(wv1.y, x1.y, a);
                a = fmaf(wv1.z, x1.z, a); a = fmaf(wv1.w, x1.w, a);
                a = fmaf(wv2.x, x2.x, a); a = fmaf(wv2.y, x2.y, a);
                a = fmaf(wv2.z, x2.z, a); a = fmaf(wv2.w, x2.w, a);
                a = fmaf(wv3.x, x3.x, a); a = fmaf(wv3.y, x3.y, a);
                a = fmaf(wv3.z, x3.z, a); a = fmaf(wv3.w, x3.w, a);
                acc[e] = a;
            }
        }
        #pragma unroll
        for (int e = 0; e < NB; ++e) {
            acc[e] += __shfl_xor(acc[e], 1);
            acc[e] += __shfl_xor(acc[e], 2);
            acc[e] += __shfl_xor(acc[e], 4);
        }
        if (c == 0) {
            const float bj = b1[j];
            #pragma unroll
            for (int e = 0; e < NB; ++e)
                y1s[e][j] = clip01(acc[e] + bj);
        }
    }
    __syncthreads();

    // ---- Phase D: layer 2 (32 -> 32) + output head; thread = (element, neuron) ----
    {
        const int e = t >> 5, i = t & 31;
        const float4* w2p = reinterpret_cast<const float4*>(W2 + i * 32);
        float a2 = b2[i];
        #pragma unroll
        for (int kq = 0; kq < 8; ++kq) {
            const float4 wq = w2p[kq];
            const float4 yq = *reinterpret_cast<const float4*>(&y1s[e][kq * 4]);
            a2 = fmaf(wq.x, yq.x, a2); a2 = fmaf(wq.y, yq.y, a2);
            a2 = fmaf(wq.z, yq.z, a2); a2 = fmaf(wq.w, yq.w, a2);
        }
        a2 = clip01(a2);
        float p = a2 * Wo[i];
        p += __shfl_xor(p, 1);  p += __shfl_xor(p, 2);
        p += __shfl_xor(p, 4);  p += __shfl_xor(p, 8);
        p += __shfl_xor(p, 16);
        if (i == 0) out[b0 + e] = p + bo[0];
    }
}

// ---------------- fallback: fp32 table path (if ws too small) ----------------
__global__ __launch_bounds__(256, 6) void nnue_fused_kernel(
    const int* __restrict__ wf, const int* __restrict__ bf,
    const float* __restrict__ stm, const float* __restrict__ table,
    const float* __restrict__ ft_bias,
    const float* __restrict__ W1, const float* __restrict__ b1,
    const float* __restrict__ W2, const float* __restrict__ b2,
    const float* __restrict__ Wo, const float* __restrict__ bo,
    float* __restrict__ out)
{
    __shared__ float4 accs[4][64];
    __shared__ float  xs[2 * 4 * 132];
    __shared__ float  y1s[2][32];

    const int t    = threadIdx.x;
    const int l    = t & 63;
    const int w    = t >> 6;
    const int side = w & 1;
    const int esub = w >> 1;

    const float4 ftb4 = reinterpret_cast<const float4*>(ft_bias)[l];
    const int*   fptr = side ? bf : wf;

    const int j = t >> 3;
    const int c = t & 7;
    const float* w1p = W1 + j * 512 + c * 64;
    const float* x0p = &xs[(0 * 4 + (c >> 1)) * 132 + (c & 1) * 64];
    const float* x1p = &xs[(1 * 4 + (c >> 1)) * 132 + (c & 1) * 64];

    for (int it = 0; it < 8 / 2; ++it) {
        const int b0 = blockIdx.x * 8 + it * 2;

        int idxv = fptr[(size_t)(b0 + esub) * KFEAT + (l & 31)];
        float4 acc = ftb4;
        #pragma unroll
        for (int k = 0; k < KFEAT; ++k) {
            const int row = __builtin_amdgcn_readlane(idxv, k);
            const float4 v = reinterpret_cast<const float4*>(table)[(size_t)row * 64 + l];
            acc.x += v.x; acc.y += v.y; acc.z += v.z; acc.w += v.w;
        }
        accs[w][l] = acc;
        __syncthreads();

        {
            const int e  = t >> 7;
            const int hf = (t >> 6) & 1;
            const int i  = t & 63;
            const float s  = stm[b0 + e];
            const float os = 1.0f - s;
            const float4 wa = accs[e * 2 + 0][i];
            const float4 ba = accs[e * 2 + 1][i];
            float4 x;
            if (hf == 0) {
                x.x = clip01(s * wa.x + os * ba.x);
                x.y = clip01(s * wa.y + os * ba.y);
                x.z = clip01(s * wa.z + os * ba.z);
                x.w = clip01(s * wa.w + os * ba.w);
            } else {
                x.x = clip01(s * ba.x + os * wa.x);
                x.y = clip01(s * ba.y + os * wa.y);
                x.z = clip01(s * ba.z + os * wa.z);
                x.w = clip01(s * ba.w + os * wa.w);
            }
            const int slot = hf * 64 + i;
            const int g = slot >> 5, i4 = slot & 31;
            *reinterpret_cast<float4*>(&xs[(e * 4 + g) * 132 + i4 * 4]) = x;
        }
        __syncthreads();

        float a0 = 0.0f, a1 = 0.0f;
        #pragma unroll 16
        for (int ii = 0; ii < 64; ++ii) {
            const float wv = w1p[ii];
            a0 = fmaf(wv, x0p[ii], a0);
            a1 = fmaf(wv, x1p[ii], a1);
        }
        a0 += __shfl_xor(a0, 1); a0 += __shfl_xor(a0, 2); a0 += __shfl_xor(a0, 4);
        a1 += __shfl_xor(a1, 1); a1 += __shfl_xor(a1, 2); a1 += __shfl_xor(a1, 4);
        if (c == 0) {
            const float bj = b1[j];
            y1s[0][j] = clip01(a0 + bj);
            y1s[1][j] = clip01(a1 + bj);
        }
        __syncthreads();

        if (t < 64) {
            const int e = t >> 5, i = t & 31;
            float a2 = b2[i];
            #pragma unroll
            for (int k2 = 0; k2 < 32; ++k2)
                a2 = fmaf(y1s[e][k2], W2[i * 32 + k2], a2);
            a2 = clip01(a2);
            float p = a2 * Wo[i];
            p += __shfl_xor(p, 1);  p += __shfl_xor(p, 2);
            p += __shfl_xor(p, 4);  p += __shfl_xor(p, 8);
            p += __shfl_xor(p, 16);
            if (i == 0) out[b0 + e] = p + bo[0];
        }
        __syncthreads();
    }
}

extern "C" void kernel_launch(void* const* d_in, const int* in_sizes, int n_in,
                              void* d_out, int out_size, void* d_ws, size_t ws_size,
                              hipStream_t stream) {
    const int*   wf      = (const int*)  d_in[0];
    const int*   bf      = (const int*)  d_in[2];
    const float* stm     = (const float*)d_in[4];
    const float* table   = (const float*)d_in[5];
    const float* ft_bias = (const float*)d_in[6];
    const float* W1      = (const float*)d_in[7];
    const float* b1      = (const float*)d_in[8];
    const float* W2      = (const float*)d_in[9];
    const float* b2      = (const float*)d_in[10];
    const float* Wo      = (const float*)d_in[11];
    const float* bo      = (const float*)d_in[12];
    float*       out     = (float*)d_out;

    const int B = in_sizes[1];                 // 16384
    const int tbl_elems = in_sizes[5];         // 40960*256
    const size_t need = (size_t)tbl_elems * sizeof(ushort);

    if (ws_size >= need) {
        ushort* tb = (ushort*)d_ws;
        convert_table_f16<<<2048, 256, 0, stream>>>(table, tb, tbl_elems / 4);
        nnue_f16_kernel<<<B / NB, 256, 0, stream>>>(
            wf, bf, stm, tb, ft_bias, W1, b1, W2, b2, Wo, bo, out);
    } else {
        nnue_fused_kernel<<<B / 8, 256, 0, stream>>>(
            wf, bf, stm, table, ft_bias, W1, b1, W2, b2, Wo, bo, out);
    }
}

// Round 8
// 61.545 us; speedup vs baseline: 1.4808x; 1.4808x over previous
//
#include <hip/hip_runtime.h>

#define KFEAT 32
#define NB 8            // batch elements per block
#define XPITCH 544      // floats per element row in xs (8 chunks * 68)
#define APITCH 272      // floats per bag row in accs overlay (= XPITCH/2)

__device__ __forceinline__ float clip01(float v) {
    return fminf(fmaxf(v, 0.0f), 1.0f);
}

// ---- one-pass per-row absmax + int8 quantize (one wave per row) ----
__global__ __launch_bounds__(256) void quantize_table_i8(
    const float* __restrict__ src, uint* __restrict__ qt,
    float* __restrict__ scales, int nrows)
{
    const int row = blockIdx.x * 4 + (threadIdx.x >> 6);
    const int l   = threadIdx.x & 63;
    if (row >= nrows) return;

    const float4 v = reinterpret_cast<const float4*>(src)[(size_t)row * 64 + l];
    float m = fmaxf(fmaxf(fabsf(v.x), fabsf(v.y)), fmaxf(fabsf(v.z), fabsf(v.w)));
    m = fmaxf(m, __shfl_xor(m, 1));
    m = fmaxf(m, __shfl_xor(m, 2));
    m = fmaxf(m, __shfl_xor(m, 4));
    m = fmaxf(m, __shfl_xor(m, 8));
    m = fmaxf(m, __shfl_xor(m, 16));
    m = fmaxf(m, __shfl_xor(m, 32));

    const float inv = (m > 0.0f) ? 127.0f / m : 0.0f;
    const int b0 = ((int)rintf(v.x * inv)) & 0xFF;
    const int b1 = ((int)rintf(v.y * inv)) & 0xFF;
    const int b2 = ((int)rintf(v.z * inv)) & 0xFF;
    const int b3 = ((int)rintf(v.w * inv)) & 0xFF;
    qt[(size_t)row * 64 + l] = (uint)b0 | ((uint)b1 << 8) | ((uint)b2 << 16) | ((uint)b3 << 24);
    if (l == 0) scales[row] = m * (1.0f / 127.0f);
}

// ---------------- main fused kernel: int8 table + per-row scale ----------------
__global__ __launch_bounds__(256, 8) void nnue_i8_kernel(
    const int* __restrict__ wf, const int* __restrict__ bf,
    const float* __restrict__ stm, const uint* __restrict__ qt,
    const float* __restrict__ scales,
    const float* __restrict__ ft_bias,
    const float* __restrict__ W1, const float* __restrict__ b1,
    const float* __restrict__ W2, const float* __restrict__ b2,
    const float* __restrict__ Wo, const float* __restrict__ bo,
    float* __restrict__ out)
{
    // Union region: first accs[16][APITCH] (raw bag sums), then xs[8][XPITCH].
    __shared__ float lds[NB * XPITCH];
    __shared__ float y1s[NB][32];

    const int t   = threadIdx.x;
    const int l   = t & 63;
    const int w   = t >> 6;     // wave 0..3
    const int sub = l & 31;
    const int b0  = blockIdx.x * NB;

    // ---- Phase A: gather 16 bags (4 per wave); one 256B int8 row per wave-load ----
    {
        const int side = w & 1;
        const int eb   = w >> 1;
        const int* fp  = side ? bf : wf;

        #pragma unroll
        for (int g = 0; g < 4; ++g) {
            const int bag  = g * 4 + w;                      // 0..15
            const int iv   = fp[(size_t)(b0 + 2 * g + eb) * KFEAT + sub];
            float a0 = 0.f, a1 = 0.f, a2 = 0.f, a3 = 0.f;
            #pragma unroll
            for (int k = 0; k < KFEAT; ++k) {
                const int row  = __builtin_amdgcn_readlane(iv, k);   // SGPR-uniform
                const int  q   = (int)qt[(size_t)row * 64 + l];
                const float sc = scales[row];                        // scalar load
                a0 = fmaf((float)((q << 24) >> 24), sc, a0);
                a1 = fmaf((float)((q << 16) >> 24), sc, a1);
                a2 = fmaf((float)((q <<  8) >> 24), sc, a2);
                a3 = fmaf((float)( q        >> 24), sc, a3);
            }
            *reinterpret_cast<float4*>(&lds[bag * APITCH + l * 4]) =
                make_float4(a0, a1, a2, a3);
        }
    }
    __syncthreads();

    // ---- Phase B: mix + clip, in-place overlay (read all -> barrier -> write) ----
    {
        const int e = t >> 5, r = t & 31;
        const float s  = stm[b0 + e];
        const float os = 1.0f - s;
        const float4 wa0 = *reinterpret_cast<const float4*>(&lds[(2 * e + 0) * APITCH + 4 * r]);
        const float4 ba0 = *reinterpret_cast<const float4*>(&lds[(2 * e + 1) * APITCH + 4 * r]);
        const float4 wa1 = *reinterpret_cast<const float4*>(&lds[(2 * e + 0) * APITCH + 4 * (r + 32)]);
        const float4 ba1 = *reinterpret_cast<const float4*>(&lds[(2 * e + 1) * APITCH + 4 * (r + 32)]);
        const float4 fb0 = reinterpret_cast<const float4*>(ft_bias)[r];
        const float4 fb1 = reinterpret_cast<const float4*>(ft_bias)[r + 32];
        __syncthreads();

        // d = hf*256 + 4*i  ->  xs addr: e*XPITCH + (d>>6)*68 + (d&63)
        #define MIXW(wa, ba, fb, i, hf)                                              \
        {                                                                            \
            float4 xv;                                                               \
            if (hf == 0) {                                                           \
                xv.x = clip01(fmaf(s, (wa).x, fmaf(os, (ba).x, (fb).x)));            \
                xv.y = clip01(fmaf(s, (wa).y, fmaf(os, (ba).y, (fb).y)));            \
                xv.z = clip01(fmaf(s, (wa).z, fmaf(os, (ba).z, (fb).z)));            \
                xv.w = clip01(fmaf(s, (wa).w, fmaf(os, (ba).w, (fb).w)));            \
            } else {                                                                 \
                xv.x = clip01(fmaf(s, (ba).x, fmaf(os, (wa).x, (fb).x)));            \
                xv.y = clip01(fmaf(s, (ba).y, fmaf(os, (wa).y, (fb).y)));            \
                xv.z = clip01(fmaf(s, (ba).z, fmaf(os, (wa).z, (fb).z)));            \
                xv.w = clip01(fmaf(s, (ba).w, fmaf(os, (wa).w, (fb).w)));            \
            }                                                                        \
            const int d = (hf) * 256 + 4 * (i);                                      \
            *reinterpret_cast<float4*>(&lds[e * XPITCH + (d >> 6) * 68 + (d & 63)]) = xv; \
        }
        MIXW(wa0, ba0, fb0, r,      0)
        MIXW(wa1, ba1, fb1, r + 32, 0)
        MIXW(wa0, ba0, fb0, r,      1)
        MIXW(wa1, ba1, fb1, r + 32, 1)
        #undef MIXW
    }
    __syncthreads();

    // ---- Phase C: layer 1 (512 -> 32) for all 8 elements; W1 read once per block ----
    {
        const int j = t >> 3;   // output neuron 0..31
        const int c = t & 7;    // 64-dim chunk 0..7
        const float* w1p = W1 + j * 512 + c * 64;
        float acc[NB] = {0.f, 0.f, 0.f, 0.f, 0.f, 0.f, 0.f, 0.f};
        #pragma unroll
        for (int blk = 0; blk < 4; ++blk) {
            const float4 wv0 = reinterpret_cast<const float4*>(w1p + blk * 16)[0];
            const float4 wv1 = reinterpret_cast<const float4*>(w1p + blk * 16)[1];
            const float4 wv2 = reinterpret_cast<const float4*>(w1p + blk * 16)[2];
            const float4 wv3 = reinterpret_cast<const float4*>(w1p + blk * 16)[3];
            #pragma unroll
            for (int e = 0; e < NB; ++e) {
                const float* xp = &lds[e * XPITCH + c * 68 + blk * 16];
                const float4 x0 = *reinterpret_cast<const float4*>(xp + 0);
                const float4 x1 = *reinterpret_cast<const float4*>(xp + 4);
                const float4 x2 = *reinterpret_cast<const float4*>(xp + 8);
                const float4 x3 = *reinterpret_cast<const float4*>(xp + 12);
                float a = acc[e];
                a = fmaf(wv0.x, x0.x, a); a = fmaf(wv0.y, x0.y, a);
                a = fmaf(wv0.z, x0.z, a); a = fmaf(wv0.w, x0.w, a);
                a = fmaf(wv1.x, x1.x, a); a = fmaf(wv1.y, x1.y, a);
                a = fmaf(wv1.z, x1.z, a); a = fmaf(wv1.w, x1.w, a);
                a = fmaf(wv2.x, x2.x, a); a = fmaf(wv2.y, x2.y, a);
                a = fmaf(wv2.z, x2.z, a); a = fmaf(wv2.w, x2.w, a);
                a = fmaf(wv3.x, x3.x, a); a = fmaf(wv3.y, x3.y, a);
                a = fmaf(wv3.z, x3.z, a); a = fmaf(wv3.w, x3.w, a);
                acc[e] = a;
            }
        }
        #pragma unroll
        for (int e = 0; e < NB; ++e) {
            acc[e] += __shfl_xor(acc[e], 1);
            acc[e] += __shfl_xor(acc[e], 2);
            acc[e] += __shfl_xor(acc[e], 4);
        }
        if (c == 0) {
            const float bj = b1[j];
            #pragma unroll
            for (int e = 0; e < NB; ++e)
                y1s[e][j] = clip01(acc[e] + bj);
        }
    }
    __syncthreads();

    // ---- Phase D: layer 2 (32 -> 32) + output head; thread = (element, neuron) ----
    {
        const int e = t >> 5, i = t & 31;
        const float4* w2p = reinterpret_cast<const float4*>(W2 + i * 32);
        float a2 = b2[i];
        #pragma unroll
        for (int kq = 0; kq < 8; ++kq) {
            const float4 wq = w2p[kq];
            const float4 yq = *reinterpret_cast<const float4*>(&y1s[e][kq * 4]);
            a2 = fmaf(wq.x, yq.x, a2); a2 = fmaf(wq.y, yq.y, a2);
            a2 = fmaf(wq.z, yq.z, a2); a2 = fmaf(wq.w, yq.w, a2);
        }
        a2 = clip01(a2);
        float p = a2 * Wo[i];
        p += __shfl_xor(p, 1);  p += __shfl_xor(p, 2);
        p += __shfl_xor(p, 4);  p += __shfl_xor(p, 8);
        p += __shfl_xor(p, 16);
        if (i == 0) out[b0 + e] = p + bo[0];
    }
}

// ---------------- fallback: fp32 table path (if ws too small) ----------------
__global__ __launch_bounds__(256, 6) void nnue_fused_kernel(
    const int* __restrict__ wf, const int* __restrict__ bf,
    const float* __restrict__ stm, const float* __restrict__ table,
    const float* __restrict__ ft_bias,
    const float* __restrict__ W1, const float* __restrict__ b1,
    const float* __restrict__ W2, const float* __restrict__ b2,
    const float* __restrict__ Wo, const float* __restrict__ bo,
    float* __restrict__ out)
{
    __shared__ float4 accs[4][64];
    __shared__ float  xs[2 * 4 * 132];
    __shared__ float  y1s[2][32];

    const int t    = threadIdx.x;
    const int l    = t & 63;
    const int w    = t >> 6;
    const int side = w & 1;
    const int esub = w >> 1;

    const float4 ftb4 = reinterpret_cast<const float4*>(ft_bias)[l];
    const int*   fptr = side ? bf : wf;

    const int j = t >> 3;
    const int c = t & 7;
    const float* w1p = W1 + j * 512 + c * 64;
    const float* x0p = &xs[(0 * 4 + (c >> 1)) * 132 + (c & 1) * 64];
    const float* x1p = &xs[(1 * 4 + (c >> 1)) * 132 + (c & 1) * 64];

    for (int it = 0; it < 8 / 2; ++it) {
        const int b0 = blockIdx.x * 8 + it * 2;

        int idxv = fptr[(size_t)(b0 + esub) * KFEAT + (l & 31)];
        float4 acc = ftb4;
        #pragma unroll
        for (int k = 0; k < KFEAT; ++k) {
            const int row = __builtin_amdgcn_readlane(idxv, k);
            const float4 v = reinterpret_cast<const float4*>(table)[(size_t)row * 64 + l];
            acc.x += v.x; acc.y += v.y; acc.z += v.z; acc.w += v.w;
        }
        accs[w][l] = acc;
        __syncthreads();

        {
            const int e  = t >> 7;
            const int hf = (t >> 6) & 1;
            const int i  = t & 63;
            const float s  = stm[b0 + e];
            const float os = 1.0f - s;
            const float4 wa = accs[e * 2 + 0][i];
            const float4 ba = accs[e * 2 + 1][i];
            float4 x;
            if (hf == 0) {
                x.x = clip01(s * wa.x + os * ba.x);
                x.y = clip01(s * wa.y + os * ba.y);
                x.z = clip01(s * wa.z + os * ba.z);
                x.w = clip01(s * wa.w + os * ba.w);
            } else {
                x.x = clip01(s * ba.x + os * wa.x);
                x.y = clip01(s * ba.y + os * wa.y);
                x.z = clip01(s * ba.z + os * wa.z);
                x.w = clip01(s * ba.w + os * wa.w);
            }
            const int slot = hf * 64 + i;
            const int g = slot >> 5, i4 = slot & 31;
            *reinterpret_cast<float4*>(&xs[(e * 4 + g) * 132 + i4 * 4]) = x;
        }
        __syncthreads();

        float a0 = 0.0f, a1 = 0.0f;
        #pragma unroll 16
        for (int ii = 0; ii < 64; ++ii) {
            const float wv = w1p[ii];
            a0 = fmaf(wv, x0p[ii], a0);
            a1 = fmaf(wv, x1p[ii], a1);
        }
        a0 += __shfl_xor(a0, 1); a0 += __shfl_xor(a0, 2); a0 += __shfl_xor(a0, 4);
        a1 += __shfl_xor(a1, 1); a1 += __shfl_xor(a1, 2); a1 += __shfl_xor(a1, 4);
        if (c == 0) {
            const float bj = b1[j];
            y1s[0][j] = clip01(a0 + bj);
            y1s[1][j] = clip01(a1 + bj);
        }
        __syncthreads();

        if (t < 64) {
            const int e = t >> 5, i = t & 31;
            float a2 = b2[i];
            #pragma unroll
            for (int k2 = 0; k2 < 32; ++k2)
                a2 = fmaf(y1s[e][k2], W2[i * 32 + k2], a2);
            a2 = clip01(a2);
            float p = a2 * Wo[i];
            p += __shfl_xor(p, 1);  p += __shfl_xor(p, 2);
            p += __shfl_xor(p, 4);  p += __shfl_xor(p, 8);
            p += __shfl_xor(p, 16);
            if (i == 0) out[b0 + e] = p + bo[0];
        }
        __syncthreads();
    }
}

extern "C" void kernel_launch(void* const* d_in, const int* in_sizes, int n_in,
                              void* d_out, int out_size, void* d_ws, size_t ws_size,
                              hipStream_t stream) {
    const int*   wf      = (const int*)  d_in[0];
    const int*   bf      = (const int*)  d_in[2];
    const float* stm     = (const float*)d_in[4];
    const float* table   = (const float*)d_in[5];
    const float* ft_bias = (const float*)d_in[6];
    const float* W1      = (const float*)d_in[7];
    const float* b1      = (const float*)d_in[8];
    const float* W2      = (const float*)d_in[9];
    const float* b2      = (const float*)d_in[10];
    const float* Wo      = (const float*)d_in[11];
    const float* bo      = (const float*)d_in[12];
    float*       out     = (float*)d_out;

    const int B = in_sizes[1];                 // 16384
    const int tbl_elems = in_sizes[5];         // 40960*256
    const int nrows = tbl_elems / 256;         // 40960
    const size_t qbytes = (size_t)tbl_elems;   // 1 byte per element
    const size_t need = qbytes + (size_t)nrows * sizeof(float);

    if (ws_size >= need) {
        uint*  qt     = (uint*)d_ws;
        float* scales = (float*)((char*)d_ws + qbytes);
        quantize_table_i8<<<(nrows + 3) / 4, 256, 0, stream>>>(table, qt, scales, nrows);
        nnue_i8_kernel<<<B / NB, 256, 0, stream>>>(
            wf, bf, stm, qt, scales, ft_bias, W1, b1, W2, b2, Wo, bo, out);
    } else {
        nnue_fused_kernel<<<B / 8, 256, 0, stream>>>(
            wf, bf, stm, table, ft_bias, W1, b1, W2, b2, Wo, bo, out);
    }
}